// Round 6
// baseline (88.708 us; speedup 1.0000x reference)
//
#include <hip/hip_runtime.h>

#define HWZ 32768   // 64*64*8 spatial positions
#define NH 8
#define HD 16

typedef __bf16 bf16x8 __attribute__((ext_vector_type(8)));
typedef unsigned short u16x8 __attribute__((ext_vector_type(8)));
typedef float f32x4 __attribute__((ext_vector_type(4)));

// ws layout (float offsets):
// [MU(128) | RS(128) | pad] | bf16 QKV (3*REGSZ u16) | bf16 w_proj^T | bf16 w_qkv^T
#define MU_OFF 0
#define RS_OFF 128
#define QKV_F_OFF 1024
#define HEADSZ (HWZ * 16)                        // ushorts per head
#define REGSZ  (NH * HEADSZ)                     // ushorts per tensor (q/k/v)
#define WT_F_OFF  (QKV_F_OFF + (3 * REGSZ) / 2)  // w_proj^T: 128x128 u16 = 8192 floats
#define WQT_F_OFF (WT_F_OFF + 8192)              // w_qkv^T: 384x128 u16 = 24576 floats

__device__ __forceinline__ unsigned short f2bf(float f) {
    unsigned int u = __builtin_bit_cast(unsigned int, f);
    unsigned int r = u + 0x7FFFu + ((u >> 16) & 1u);   // RNE
    return (unsigned short)(r >> 16);
}
__device__ __forceinline__ float bf2f(unsigned short s) {
    unsigned int u = ((unsigned int)s) << 16;
    return __builtin_bit_cast(float, u);
}

// ---------------- per-channel mean / rsqrt(var) ----------------
__global__ void stats_kernel(const float* __restrict__ x, float* __restrict__ ws) {
    int ch = blockIdx.x;
    const float4* xp = (const float4*)(x + (size_t)ch * HWZ);
    float s = 0.f, ss = 0.f;
    for (int i = threadIdx.x; i < HWZ / 4; i += blockDim.x) {
        float4 v = xp[i];
        s  += v.x + v.y + v.z + v.w;
        ss += v.x*v.x + v.y*v.y + v.z*v.z + v.w*v.w;
    }
    for (int off = 32; off; off >>= 1) {
        s  += __shfl_down(s, off);
        ss += __shfl_down(ss, off);
    }
    __shared__ float as_[4], bs_[4];
    int lane = threadIdx.x & 63, wid = threadIdx.x >> 6;
    if (lane == 0) { as_[wid] = s; bs_[wid] = ss; }
    __syncthreads();
    if (threadIdx.x == 0) {
        float S = 0.f, SS = 0.f;
        for (int w = 0; w < 4; w++) { S += as_[w]; SS += bs_[w]; }
        float mu  = S / (float)HWZ;
        float var = SS / (float)HWZ - mu * mu;
        ws[MU_OFF + ch] = mu;
        ws[RS_OFF + ch] = rsqrtf(var + 1e-5f);
    }
}

// ---------------- pre-transpose both weight matrices to bf16 [j][c] images ----------------
__global__ void wprep_kernel(const float* __restrict__ w_qkv,
                             const float* __restrict__ w_proj,
                             float* __restrict__ ws) {
    int b = blockIdx.x;        // 0..511
    int c = threadIdx.x;       // 0..127
    if (b < 384) {
        unsigned short* wqt = (unsigned short*)(ws + WQT_F_OFF);
        wqt[b * 128 + c] = f2bf(w_qkv[(size_t)c * 384 + b]);
    } else {
        int j = b - 384;
        unsigned short* wpt = (unsigned short*)(ws + WT_F_OFF);
        wpt[j * 128 + c] = f2bf(w_proj[(size_t)c * 128 + j]);
    }
}

// ---------------- QKV GEMM via bf16 MFMA, B fragments straight from global ----------------
__global__ __launch_bounds__(512) void qkv_kernel(const float* __restrict__ x,
                                                  const float* __restrict__ b_qkv,
                                                  float* __restrict__ ws) {
    __shared__ unsigned short xs[64 * 128];    // [p][c] bf16, 16B groups XOR-swizzled by p&15
    const int tid = threadIdx.x;
    const int p0 = blockIdx.x * 64;

#pragma unroll
    for (int it = 0; it < 4; it++) {
        int i = tid + it * 512;
        int c = i >> 4, pq = (i & 15) * 4;
        float mu = ws[MU_OFF + c], rs = ws[RS_OFF + c];
        float4 v = *(const float4*)(x + (size_t)c * HWZ + p0 + pq);
        int c8 = c >> 3, cl = c & 7;
        float vv[4] = {v.x, v.y, v.z, v.w};
#pragma unroll
        for (int e = 0; e < 4; e++) {
            int p = pq + e;
            xs[p * 128 + ((c8 ^ (p & 15)) << 3) + cl] = f2bf((vv[e] - mu) * rs);
        }
    }
    __syncthreads();

    const int wv   = tid >> 6;
    const int lane = tid & 63;
    const int col  = lane & 15;
    const int kgrp = lane >> 4;
    const int ptile = wv & 3;
    const int jq    = wv >> 2;
    const unsigned short* arow = xs + (ptile * 16 + col) * 128;
    const int arow15 = (ptile * 16 + col) & 15;

    u16x8 a[4];
#pragma unroll
    for (int ks = 0; ks < 4; ks++) {
        a[ks] = *(const u16x8*)(arow + (((ks * 4 + kgrp) ^ arow15) << 3));
    }

    const unsigned short* wqt = (const unsigned short*)(ws + WQT_F_OFF);
    unsigned short* qkvb = (unsigned short*)(ws + QKV_F_OFF);

    for (int chunk = 0; chunk < 3; chunk++) {
        float scale = (chunk == 0) ? 0.25f : 1.0f;
        unsigned short* dstbase = qkvb + (size_t)chunk * REGSZ;
#pragma unroll
        for (int jt = 0; jt < 4; jt++) {
            int jl = jq * 64 + jt * 16 + col;
            const unsigned short* brow = wqt + (size_t)(chunk * 128 + jl) * 128;
            f32x4 acc = {0.f, 0.f, 0.f, 0.f};
#pragma unroll
            for (int ks = 0; ks < 4; ks++) {
                u16x8 b = *(const u16x8*)(brow + ((ks * 4 + kgrp) << 3));
                acc = __builtin_amdgcn_mfma_f32_16x16x32_bf16(
                        __builtin_bit_cast(bf16x8, a[ks]),
                        __builtin_bit_cast(bf16x8, b), acc, 0, 0, 0);
            }
            int head = jq * 4 + jt;
            float bias = b_qkv[chunk * 128 + head * 16 + col];
            unsigned short* dst = dstbase + (size_t)head * HEADSZ + col;
#pragma unroll
            for (int i = 0; i < 4; i++) {
                int p = p0 + ptile * 16 + kgrp * 4 + i;
                dst[(size_t)p * 16] = f2bf((acc[i] + bias) * scale);
            }
        }
    }
}

// ---------------- fused NATTEN attention + output projection ----------------
// block: 256 thr = 32 positions x 8 heads; per-thread attention via L1/L2
// gathers, o -> bf16 LDS [pl][c]; proj GEMM via MFMA, B from global image.
__global__ __launch_bounds__(256) void attnproj_kernel(const float* __restrict__ rpb,
                                                       const float* __restrict__ b_proj,
                                                       float* __restrict__ ws,
                                                       float* __restrict__ out) {
    __shared__ unsigned short aol[32 * 128];   // 8 KB
    const int tid = threadIdx.x;
    const int p0 = blockIdx.x * 32;
    const int pl = tid & 31, head = tid >> 5;
    const int p = p0 + pl;
    int zi = p & 7, wi = (p >> 3) & 63, hi = p >> 9;
    int sh = min(max(hi - 1, 0), 61);
    int sw = min(max(wi - 1, 0), 61);
    int sz = min(max(zi - 1, 0), 5);

    const unsigned short* qkvb = (const unsigned short*)(ws + QKV_F_OFF);
    const unsigned short* qp = qkvb + (size_t)head * HEADSZ + (size_t)p * 16;
    float q[16];
#pragma unroll
    for (int h8 = 0; h8 < 2; h8++) {
        u16x8 v = *(const u16x8*)(qp + h8 * 8);
#pragma unroll
        for (int e = 0; e < 8; e++) q[h8 * 8 + e] = bf2f(v[e]);
    }
    const unsigned short* kbase = qkvb + REGSZ + (size_t)head * HEADSZ;
    const unsigned short* vbase = qkvb + 2 * (size_t)REGSZ + (size_t)head * HEADSZ;
    const float* rp = rpb + head * 125 + (sh - hi + 2) * 25 + (sw - wi + 2) * 5 + (sz - zi + 2);

    float l[27];
    float m = -1e30f;
#pragma unroll
    for (int a = 0; a < 3; a++)
#pragma unroll
    for (int b = 0; b < 3; b++)
#pragma unroll
    for (int c = 0; c < 3; c++) {
        int np_ = (sh + a) * 512 + (sw + b) * 8 + (sz + c);
        const unsigned short* kp = kbase + (size_t)np_ * 16;
        float dot = 0.f;
#pragma unroll
        for (int h8 = 0; h8 < 2; h8++) {
            u16x8 kv = *(const u16x8*)(kp + h8 * 8);
#pragma unroll
            for (int e = 0; e < 8; e++) dot += q[h8 * 8 + e] * bf2f(kv[e]);
        }
        float lg = dot + rp[a * 25 + b * 5 + c];
        l[a*9 + b*3 + c] = lg;
        m = fmaxf(m, lg);
    }
    float s = 0.f;
#pragma unroll
    for (int n = 0; n < 27; n++) { l[n] = expf(l[n] - m); s += l[n]; }
    float inv = 1.f / s;

    float o[16];
#pragma unroll
    for (int d = 0; d < 16; d++) o[d] = 0.f;
#pragma unroll
    for (int a = 0; a < 3; a++)
#pragma unroll
    for (int b = 0; b < 3; b++)
#pragma unroll
    for (int c = 0; c < 3; c++) {
        int np_ = (sh + a) * 512 + (sw + b) * 8 + (sz + c);
        const unsigned short* vp = vbase + (size_t)np_ * 16;
        float w = l[a*9 + b*3 + c];
#pragma unroll
        for (int h8 = 0; h8 < 2; h8++) {
            u16x8 vv = *(const u16x8*)(vp + h8 * 8);
#pragma unroll
            for (int e = 0; e < 8; e++) o[h8 * 8 + e] += w * bf2f(vv[e]);
        }
    }

    // write attention output to LDS [pl][c] bf16, 16B groups swizzled by pl&15
    {
        u16x8 lo, hi_;
#pragma unroll
        for (int e = 0; e < 8; e++) {
            lo[e]  = f2bf(o[e] * inv);
            hi_[e] = f2bf(o[8 + e] * inv);
        }
        int r15 = pl & 15;
        *(u16x8*)(aol + pl * 128 + (((head * 2)     ^ r15) << 3)) = lo;
        *(u16x8*)(aol + pl * 128 + (((head * 2 + 1) ^ r15) << 3)) = hi_;
    }
    __syncthreads();

    // proj GEMM: out[p][j] = sum_c' ao[p][c'] * wT[j][c'], B from global image
    const unsigned short* wpt = (const unsigned short*)(ws + WT_F_OFF);
    const int lane = tid & 63, wv = tid >> 6;
    const int col = lane & 15, kgrp = lane >> 4;
    const int ptile = wv & 1, jhalf = wv >> 1;
    const int arow = ptile * 16 + col;
    const unsigned short* ap = aol + arow * 128;
    u16x8 a[4];
#pragma unroll
    for (int ks = 0; ks < 4; ks++) {
        a[ks] = *(const u16x8*)(ap + (((ks * 4 + kgrp) ^ (arow & 15)) << 3));
    }
#pragma unroll
    for (int jt = 0; jt < 4; jt++) {
        int j = jhalf * 64 + jt * 16 + col;
        const unsigned short* bp = wpt + j * 128;
        f32x4 acc = {0.f, 0.f, 0.f, 0.f};
#pragma unroll
        for (int ks = 0; ks < 4; ks++) {
            u16x8 b = *(const u16x8*)(bp + ((ks * 4 + kgrp) << 3));
            acc = __builtin_amdgcn_mfma_f32_16x16x32_bf16(
                    __builtin_bit_cast(bf16x8, a[ks]),
                    __builtin_bit_cast(bf16x8, b), acc, 0, 0, 0);
        }
        float bias = b_proj[j];
        float4 o4;
        o4.x = acc[0] + bias; o4.y = acc[1] + bias;
        o4.z = acc[2] + bias; o4.w = acc[3] + bias;
        *(float4*)(out + (size_t)j * HWZ + p0 + ptile * 16 + kgrp * 4) = o4;
    }
}

extern "C" void kernel_launch(void* const* d_in, const int* in_sizes, int n_in,
                              void* d_out, int out_size, void* d_ws, size_t ws_size,
                              hipStream_t stream) {
    const float* x      = (const float*)d_in[0];
    const float* w_qkv  = (const float*)d_in[1];
    const float* b_qkv  = (const float*)d_in[2];
    const float* rpb    = (const float*)d_in[3];
    const float* w_proj = (const float*)d_in[4];
    const float* b_proj = (const float*)d_in[5];
    float* out = (float*)d_out;
    float* ws  = (float*)d_ws;

    wprep_kernel<<<512, 128, 0, stream>>>(w_qkv, w_proj, ws);
    stats_kernel<<<128, 256, 0, stream>>>(x, ws);
    qkv_kernel<<<512, 512, 0, stream>>>(x, b_qkv, ws);
    attnproj_kernel<<<1024, 256, 0, stream>>>(rpb, b_proj, ws, out);
}

// Round 8
// 79.297 us; speedup vs baseline: 1.1187x; 1.1187x over previous
//
#include <hip/hip_runtime.h>

#define HWZ 32768   // 64*64*8 spatial positions
#define NH 8
#define HD 16

typedef __bf16 bf16x8 __attribute__((ext_vector_type(8)));
typedef unsigned short u16x8 __attribute__((ext_vector_type(8)));
typedef unsigned short u16x4 __attribute__((ext_vector_type(4)));
typedef short s16x4 __attribute__((ext_vector_type(4)));
typedef float f32x4 __attribute__((ext_vector_type(4)));

// ws layout (float offsets):
// [MU(128) | RS(128) | pad] | bf16 QKV (3*REGSZ u16) | bf16 w_proj^T | bf16 w_qkv^T
// Q: [head][p][d]   K: [head][p][d]   V: [head][d][p]  (transposed!)
#define MU_OFF 0
#define RS_OFF 128
#define QKV_F_OFF 1024
#define HEADSZ (HWZ * 16)                        // ushorts per head
#define REGSZ  (NH * HEADSZ)                     // ushorts per tensor (q/k/v)
#define WT_F_OFF  (QKV_F_OFF + (3 * REGSZ) / 2)  // w_proj^T: 128x128 u16
#define WQT_F_OFF (WT_F_OFF + 8192)              // w_qkv^T: 384x128 u16

__device__ __forceinline__ unsigned short f2bf(float f) {
    unsigned int u = __builtin_bit_cast(unsigned int, f);
    unsigned int r = u + 0x7FFFu + ((u >> 16) & 1u);   // RNE
    return (unsigned short)(r >> 16);
}

// ---------------- per-channel mean / rsqrt(var) ----------------
__global__ void stats_kernel(const float* __restrict__ x, float* __restrict__ ws) {
    int ch = blockIdx.x;
    const float4* xp = (const float4*)(x + (size_t)ch * HWZ);
    float s = 0.f, ss = 0.f;
    for (int i = threadIdx.x; i < HWZ / 4; i += blockDim.x) {
        float4 v = xp[i];
        s  += v.x + v.y + v.z + v.w;
        ss += v.x*v.x + v.y*v.y + v.z*v.z + v.w*v.w;
    }
    for (int off = 32; off; off >>= 1) {
        s  += __shfl_down(s, off);
        ss += __shfl_down(ss, off);
    }
    __shared__ float as_[4], bs_[4];
    int lane = threadIdx.x & 63, wid = threadIdx.x >> 6;
    if (lane == 0) { as_[wid] = s; bs_[wid] = ss; }
    __syncthreads();
    if (threadIdx.x == 0) {
        float S = 0.f, SS = 0.f;
        for (int w = 0; w < 4; w++) { S += as_[w]; SS += bs_[w]; }
        float mu  = S / (float)HWZ;
        float var = SS / (float)HWZ - mu * mu;
        ws[MU_OFF + ch] = mu;
        ws[RS_OFF + ch] = rsqrtf(var + 1e-5f);
    }
}

// ---------------- pre-transpose both weight matrices to bf16 [j][c] images ----------------
__global__ void wprep_kernel(const float* __restrict__ w_qkv,
                             const float* __restrict__ w_proj,
                             float* __restrict__ ws) {
    int b = blockIdx.x;        // 0..511
    int c = threadIdx.x;       // 0..127
    if (b < 384) {
        unsigned short* wqt = (unsigned short*)(ws + WQT_F_OFF);
        wqt[b * 128 + c] = f2bf(w_qkv[(size_t)c * 384 + b]);
    } else {
        int j = b - 384;
        unsigned short* wpt = (unsigned short*)(ws + WT_F_OFF);
        wpt[j * 128 + c] = f2bf(w_proj[(size_t)c * 128 + j]);
    }
}

// ---------------- QKV GEMM via bf16 MFMA ----------------
__global__ __launch_bounds__(512) void qkv_kernel(const float* __restrict__ x,
                                                  const float* __restrict__ b_qkv,
                                                  float* __restrict__ ws) {
    __shared__ unsigned short xs[64 * 128];    // [p][c] bf16, 16B groups XOR-swizzled by p&15
    const int tid = threadIdx.x;
    const int p0 = blockIdx.x * 64;

#pragma unroll
    for (int it = 0; it < 4; it++) {
        int i = tid + it * 512;
        int c = i >> 4, pq = (i & 15) * 4;
        float mu = ws[MU_OFF + c], rs = ws[RS_OFF + c];
        float4 v = *(const float4*)(x + (size_t)c * HWZ + p0 + pq);
        int c8 = c >> 3, cl = c & 7;
        float vv[4] = {v.x, v.y, v.z, v.w};
#pragma unroll
        for (int e = 0; e < 4; e++) {
            int p = pq + e;
            xs[p * 128 + ((c8 ^ (p & 15)) << 3) + cl] = f2bf((vv[e] - mu) * rs);
        }
    }
    __syncthreads();

    const int wv   = tid >> 6;
    const int lane = tid & 63;
    const int col  = lane & 15;
    const int kgrp = lane >> 4;
    const int ptile = wv & 3;
    const int jq    = wv >> 2;
    const unsigned short* arow = xs + (ptile * 16 + col) * 128;
    const int arow15 = (ptile * 16 + col) & 15;

    u16x8 a[4];
#pragma unroll
    for (int ks = 0; ks < 4; ks++) {
        a[ks] = *(const u16x8*)(arow + (((ks * 4 + kgrp) ^ arow15) << 3));
    }

    const unsigned short* wqt = (const unsigned short*)(ws + WQT_F_OFF);
    unsigned short* qkvb = (unsigned short*)(ws + QKV_F_OFF);

    for (int chunk = 0; chunk < 3; chunk++) {
        float scale = (chunk == 0) ? 0.25f : 1.0f;
#pragma unroll
        for (int jt = 0; jt < 4; jt++) {
            int jl = jq * 64 + jt * 16 + col;
            const unsigned short* brow = wqt + (size_t)(chunk * 128 + jl) * 128;
            f32x4 acc = {0.f, 0.f, 0.f, 0.f};
#pragma unroll
            for (int ks = 0; ks < 4; ks++) {
                u16x8 b = *(const u16x8*)(brow + ((ks * 4 + kgrp) << 3));
                acc = __builtin_amdgcn_mfma_f32_16x16x32_bf16(
                        __builtin_bit_cast(bf16x8, a[ks]),
                        __builtin_bit_cast(bf16x8, b), acc, 0, 0, 0);
            }
            int head = jq * 4 + jt;
            float bias = b_qkv[chunk * 128 + head * 16 + col];
            if (chunk == 2) {
                // V transposed: vt[head][d=col][p], 4 consecutive p -> one 8B store
                unsigned short* vt = qkvb + 2 * (size_t)REGSZ
                                   + ((size_t)(head * 16 + col)) * HWZ
                                   + p0 + ptile * 16 + kgrp * 4;
                u16x4 o;
#pragma unroll
                for (int i = 0; i < 4; i++) o[i] = f2bf(acc[i] + bias);
                *(u16x4*)vt = o;
            } else {
                unsigned short* dst = qkvb + (size_t)chunk * REGSZ + (size_t)head * HEADSZ + col;
#pragma unroll
                for (int i = 0; i < 4; i++) {
                    int p = p0 + ptile * 16 + kgrp * 4 + i;
                    dst[(size_t)p * 16] = f2bf((acc[i] + bias) * scale);
                }
            }
        }
    }
}

// ---------------- fused NATTEN attention (MFMA) + output projection ----------------
// block: 512 thr = 8 waves = 8 heads; 16 queries (1h x 2w x 8z tile).
// Key candidates: h anchored at sh (3 rows, always valid since window is
// clamped), w grid w0-1..w0+2 (mask covers clamping), all 8 z.
// logits = K @ Q^T (16x16x16 MFMA), masked bias softmax in-register,
// P accum layout == B operand layout -> PV = V^T @ P, then fused proj GEMM.
__global__ __launch_bounds__(512) void attnproj_kernel(const float* __restrict__ rpb,
                                                       const float* __restrict__ b_proj,
                                                       float* __restrict__ ws,
                                                       float* __restrict__ out) {
    __shared__ unsigned short aol[16 * 128];   // 4 KB attention-out bf16
    __shared__ float rpb_s[8 * 128];           // 4 KB bias tables
    const int tid = threadIdx.x;

    for (int i = tid; i < 1024; i += 512) {
        int hh = i >> 7, e = i & 127;
        rpb_s[i] = (e < 125) ? rpb[hh * 125 + e] : 0.f;
    }
    __syncthreads();

    const int p0 = blockIdx.x * 16;
    const int h0 = p0 >> 9;
    const int w0 = (p0 >> 3) & 63;
    const int wv = tid >> 6, lane = tid & 63;
    const int head = wv;
    const int g = lane >> 4;          // row-group
    const int qcol = lane & 15;       // query (as C-col / B-col); also key-row for A loads
    const int lw = qcol >> 3, qz = qcol & 7;
    const int w = w0 + lw, z = qz;

    // ANCHORED h window: rows sh..sh+2 are exactly the reference window (h uniform)
    const int sh = min(max(h0 - 1, 0), 61);
    const int dh = sh - h0 + 2;       // bias row offset for ih=0
    // per-query w/z window starts
    const int sw = min(max(w - 1, 0), 61);
    const int sz = min(max(z - 1, 0), 5);

    // validity bitmasks over the w/z key grid (h always valid)
    unsigned wmask = 0, zmask = 0;
#pragma unroll
    for (int iw = 0; iw < 4; iw++) {
        int W = w0 - 1 + iw;
        if (W >= sw && W <= sw + 2) wmask |= 1u << iw;
    }
#pragma unroll
    for (int zp = 0; zp < 8; zp++) {
        if (zp >= sz && zp <= sz + 2) zmask |= 1u << zp;
    }

    int Wc[4];
#pragma unroll
    for (int iw = 0; iw < 4; iw++) Wc[iw] = min(max(w0 - 1 + iw, 0), 63);

    const unsigned short* qkvb = (const unsigned short*)(ws + QKV_F_OFF);
    const unsigned short* qbase = qkvb + (size_t)head * HEADSZ;
    const unsigned short* kbase = qkvb + (size_t)REGSZ + (size_t)head * HEADSZ;
    const unsigned short* vtb  = qkvb + 2 * (size_t)REGSZ + (size_t)(head * 16) * HWZ;

    // Q B-fragment: B[k=d][n=q], lane col=q holds d = 4g..4g+3
    s16x4 bq = *(const s16x4*)(qbase + (size_t)(p0 + qcol) * 16 + g * 4);

    // ---- logits: 6 Mtiles of K(16 keys) @ Q^T ----
    const int iwlA = qcol >> 3, zpA = qcol & 7;   // A-row decode (key row = lane&15)
    f32x4 acc[6];
#pragma unroll
    for (int mt = 0; mt < 6; mt++) {
        int iwA = (mt & 1) * 2 + iwlA;
        int pk = (sh + (mt >> 1)) * 512 + Wc[iwA] * 8 + zpA;
        s16x4 ak = *(const s16x4*)(kbase + (size_t)pk * 16 + g * 4);
        f32x4 zero = {0.f, 0.f, 0.f, 0.f};
        acc[mt] = __builtin_amdgcn_mfma_f32_16x16x16bf16_1k(ak, bq, zero, 0, 0, 0);
    }

    // ---- mask + bias + softmax (per C-element: key row = 4g+r, query col = qcol) ----
    const float* bt = rpb_s + head * 128;
    float lv[24];
    float lmax = -1e30f;
#pragma unroll
    for (int mt = 0; mt < 6; mt++) {
        int ih = mt >> 1;
#pragma unroll
        for (int r = 0; r < 4; r++) {
            int krow = g * 4 + r;
            int iw = (mt & 1) * 2 + (krow >> 3);
            int zp = krow & 7;
            int ok = ((wmask >> iw) & 1) & ((zmask >> zp) & 1);
            int idx = (dh + ih) * 25 + (iw + 1 - lw) * 5 + (zp - z + 2);
            idx = ok ? idx : 62;
            float lg = ok ? (acc[mt][r] + bt[idx]) : -1e30f;
            lv[mt * 4 + r] = lg;
            lmax = fmaxf(lmax, lg);
        }
    }
    lmax = fmaxf(lmax, __shfl_xor(lmax, 16));
    lmax = fmaxf(lmax, __shfl_xor(lmax, 32));
    float ssum = 0.f;
#pragma unroll
    for (int i = 0; i < 24; i++) {
        float pexp = __expf(lv[i] - lmax);
        lv[i] = pexp;
        ssum += pexp;
    }
    ssum += __shfl_xor(ssum, 16);
    ssum += __shfl_xor(ssum, 32);
    float inv = 1.f / ssum;

    // P -> bf16 fragments (B operand layout matches accumulator layout exactly)
    s16x4 pb[6];
#pragma unroll
    for (int mt = 0; mt < 6; mt++)
#pragma unroll
        for (int r = 0; r < 4; r++)
            pb[mt][r] = (short)f2bf(lv[mt * 4 + r]);

    // ---- PV: out(16d x 16q) = V^T @ P, K=96 chained ----
    const int iwlV = g >> 1, zp0V = (g & 1) * 4;   // A k-decode: keys 4g..4g+3
    f32x4 oacc = {0.f, 0.f, 0.f, 0.f};
#pragma unroll
    for (int mt = 0; mt < 6; mt++) {
        int iwV = (mt & 1) * 2 + iwlV;
        int pk = (sh + (mt >> 1)) * 512 + Wc[iwV] * 8 + zp0V;
        s16x4 av = *(const s16x4*)(vtb + (size_t)qcol * HWZ + pk);
        oacc = __builtin_amdgcn_mfma_f32_16x16x16bf16_1k(av, pb[mt], oacc, 0, 0, 0);
    }

    // write to aol[q][c], 16B groups swizzled by q&15 (c = head*16 + d, d = 4g+r)
#pragma unroll
    for (int r = 0; r < 4; r++) {
        int c = head * 16 + g * 4 + r;
        aol[qcol * 128 + (((c >> 3) ^ qcol) << 3) + (c & 7)] = f2bf(oacc[r] * inv);
    }
    __syncthreads();

    // ---- proj GEMM: out[p][j] = sum_c' ao[p][c'] * wT[j][c'], wave wv = jtile ----
    const unsigned short* wpt = (const unsigned short*)(ws + WT_F_OFF);
    const unsigned short* ap = aol + qcol * 128;   // A row = position = lane&15
    u16x8 a[4];
#pragma unroll
    for (int ks = 0; ks < 4; ks++) {
        a[ks] = *(const u16x8*)(ap + (((ks * 4 + g) ^ qcol) << 3));
    }
    int j = wv * 16 + qcol;
    const unsigned short* bp = wpt + j * 128;
    f32x4 pacc = {0.f, 0.f, 0.f, 0.f};
#pragma unroll
    for (int ks = 0; ks < 4; ks++) {
        u16x8 b = *(const u16x8*)(bp + ((ks * 4 + g) << 3));
        pacc = __builtin_amdgcn_mfma_f32_16x16x32_bf16(
                __builtin_bit_cast(bf16x8, a[ks]),
                __builtin_bit_cast(bf16x8, b), pacc, 0, 0, 0);
    }
    float bias = b_proj[j];
    float4 o4;
    o4.x = pacc[0] + bias; o4.y = pacc[1] + bias;
    o4.z = pacc[2] + bias; o4.w = pacc[3] + bias;
    *(float4*)(out + (size_t)j * HWZ + p0 + g * 4) = o4;
}

extern "C" void kernel_launch(void* const* d_in, const int* in_sizes, int n_in,
                              void* d_out, int out_size, void* d_ws, size_t ws_size,
                              hipStream_t stream) {
    const float* x      = (const float*)d_in[0];
    const float* w_qkv  = (const float*)d_in[1];
    const float* b_qkv  = (const float*)d_in[2];
    const float* rpb    = (const float*)d_in[3];
    const float* w_proj = (const float*)d_in[4];
    const float* b_proj = (const float*)d_in[5];
    float* out = (float*)d_out;
    float* ws  = (float*)d_ws;

    wprep_kernel<<<512, 128, 0, stream>>>(w_qkv, w_proj, ws);
    stats_kernel<<<128, 256, 0, stream>>>(x, ws);
    qkv_kernel<<<512, 512, 0, stream>>>(x, b_qkv, ws);
    attnproj_kernel<<<2048, 512, 0, stream>>>(rpb, b_proj, ws, out);
}

// Round 10
// 74.285 us; speedup vs baseline: 1.1942x; 1.0675x over previous
//
#include <hip/hip_runtime.h>

#define HWZ 32768   // 64*64*8 spatial positions
#define NH 8
#define HD 16

typedef __bf16 bf16x8 __attribute__((ext_vector_type(8)));
typedef unsigned short u16x8 __attribute__((ext_vector_type(8)));
typedef unsigned short u16x4 __attribute__((ext_vector_type(4)));
typedef short s16x4 __attribute__((ext_vector_type(4)));
typedef float f32x4 __attribute__((ext_vector_type(4)));

// ws layout (float offsets):
// [MU(128) | RS(128) | pad] | bf16 QKV (3*REGSZ u16) | bf16 w_proj^T | bf16 w_qkv^T
// Q: [head][p][d]   K: [head][p][d]   V: [head][d][p]  (transposed!)
#define MU_OFF 0
#define RS_OFF 128
#define QKV_F_OFF 1024
#define HEADSZ (HWZ * 16)                        // ushorts per head
#define REGSZ  (NH * HEADSZ)                     // ushorts per tensor (q/k/v)
#define WT_F_OFF  (QKV_F_OFF + (3 * REGSZ) / 2)  // w_proj^T: 128x128 u16
#define WQT_F_OFF (WT_F_OFF + 8192)              // w_qkv^T: 384x128 u16

__device__ __forceinline__ unsigned short f2bf(float f) {
    unsigned int u = __builtin_bit_cast(unsigned int, f);
    unsigned int r = u + 0x7FFFu + ((u >> 16) & 1u);   // RNE
    return (unsigned short)(r >> 16);
}

// ---------------- merged: per-channel stats (blocks 0..127) + weight transpose (128..383) ----------------
__global__ __launch_bounds__(256) void prep_kernel(const float* __restrict__ x,
                                                   const float* __restrict__ w_qkv,
                                                   const float* __restrict__ w_proj,
                                                   float* __restrict__ ws) {
    int blk = blockIdx.x;
    if (blk < 128) {
        int ch = blk;
        const float4* xp = (const float4*)(x + (size_t)ch * HWZ);
        float s = 0.f, ss = 0.f;
        for (int i = threadIdx.x; i < HWZ / 4; i += 256) {
            float4 v = xp[i];
            s  += v.x + v.y + v.z + v.w;
            ss += v.x*v.x + v.y*v.y + v.z*v.z + v.w*v.w;
        }
        for (int off = 32; off; off >>= 1) {
            s  += __shfl_down(s, off);
            ss += __shfl_down(ss, off);
        }
        __shared__ float as_[4], bs_[4];
        int lane = threadIdx.x & 63, wid = threadIdx.x >> 6;
        if (lane == 0) { as_[wid] = s; bs_[wid] = ss; }
        __syncthreads();
        if (threadIdx.x == 0) {
            float S = 0.f, SS = 0.f;
            for (int w = 0; w < 4; w++) { S += as_[w]; SS += bs_[w]; }
            float mu  = S / (float)HWZ;
            float var = SS / (float)HWZ - mu * mu;
            ws[MU_OFF + ch] = mu;
            ws[RS_OFF + ch] = rsqrtf(var + 1e-5f);
        }
    } else {
        int rr = (blk - 128) * 2 + (threadIdx.x >> 7);   // 0..511 (grid=384 -> exact)
        int c  = threadIdx.x & 127;
        if (rr < 384) {
            unsigned short* wqt = (unsigned short*)(ws + WQT_F_OFF);
            wqt[rr * 128 + c] = f2bf(w_qkv[(size_t)c * 384 + rr]);
        } else if (rr < 512) {
            int j = rr - 384;
            unsigned short* wpt = (unsigned short*)(ws + WT_F_OFF);
            wpt[j * 128 + c] = f2bf(w_proj[(size_t)c * 128 + j]);
        }
    }
}

// ---------------- QKV GEMM via bf16 MFMA ----------------
__global__ __launch_bounds__(512) void qkv_kernel(const float* __restrict__ x,
                                                  const float* __restrict__ b_qkv,
                                                  float* __restrict__ ws) {
    __shared__ unsigned short xs[64 * 128];    // [p][c] bf16, 16B groups XOR-swizzled by p&15
    const int tid = threadIdx.x;
    const int p0 = blockIdx.x * 64;

    // staging: thread = (cgrp, pgrp); 4 rows x 4 positions, vectorized 8B LDS writes
    {
        const int pgrp = tid & 15;        // p = pgrp*4 .. +3
        const int c0   = (tid >> 4) * 4;  // c = c0 .. c0+3
        float4 mu4 = *(const float4*)(ws + MU_OFF + c0);
        float4 rs4 = *(const float4*)(ws + RS_OFF + c0);
        float mus[4] = {mu4.x, mu4.y, mu4.z, mu4.w};
        float rss[4] = {rs4.x, rs4.y, rs4.z, rs4.w};
        unsigned short vals[4][4];        // [ci][pi]
#pragma unroll
        for (int ci = 0; ci < 4; ci++) {
            float4 v = *(const float4*)(x + (size_t)(c0 + ci) * HWZ + p0 + pgrp * 4);
            vals[ci][0] = f2bf((v.x - mus[ci]) * rss[ci]);
            vals[ci][1] = f2bf((v.y - mus[ci]) * rss[ci]);
            vals[ci][2] = f2bf((v.z - mus[ci]) * rss[ci]);
            vals[ci][3] = f2bf((v.w - mus[ci]) * rss[ci]);
        }
        const int c8 = c0 >> 3, cl = c0 & 7;   // cl in {0,4}: 8B-aligned within 16B group
#pragma unroll
        for (int pi = 0; pi < 4; pi++) {
            int p = pgrp * 4 + pi;
            u16x4 o = {vals[0][pi], vals[1][pi], vals[2][pi], vals[3][pi]};
            *(u16x4*)(xs + p * 128 + ((c8 ^ (p & 15)) << 3) + cl) = o;
        }
    }
    __syncthreads();

    const int wv   = tid >> 6;
    const int lane = tid & 63;
    const int col  = lane & 15;
    const int kgrp = lane >> 4;
    const int ptile = wv & 3;
    const int jq    = wv >> 2;
    const unsigned short* arow = xs + (ptile * 16 + col) * 128;
    const int arow15 = (ptile * 16 + col) & 15;

    u16x8 a[4];
#pragma unroll
    for (int ks = 0; ks < 4; ks++) {
        a[ks] = *(const u16x8*)(arow + (((ks * 4 + kgrp) ^ arow15) << 3));
    }

    const unsigned short* wqt = (const unsigned short*)(ws + WQT_F_OFF);
    unsigned short* qkvb = (unsigned short*)(ws + QKV_F_OFF);

    for (int chunk = 0; chunk < 3; chunk++) {
        float scale = (chunk == 0) ? 0.25f : 1.0f;
#pragma unroll
        for (int jt = 0; jt < 4; jt++) {
            int jl = jq * 64 + jt * 16 + col;
            const unsigned short* brow = wqt + (size_t)(chunk * 128 + jl) * 128;
            f32x4 acc = {0.f, 0.f, 0.f, 0.f};
#pragma unroll
            for (int ks = 0; ks < 4; ks++) {
                u16x8 b = *(const u16x8*)(brow + ((ks * 4 + kgrp) << 3));
                acc = __builtin_amdgcn_mfma_f32_16x16x32_bf16(
                        __builtin_bit_cast(bf16x8, a[ks]),
                        __builtin_bit_cast(bf16x8, b), acc, 0, 0, 0);
            }
            int head = jq * 4 + jt;
            float bias = b_qkv[chunk * 128 + head * 16 + col];
            if (chunk == 2) {
                // V transposed: vt[head][d=col][p]
                unsigned short* vt = qkvb + 2 * (size_t)REGSZ
                                   + ((size_t)(head * 16 + col)) * HWZ
                                   + p0 + ptile * 16 + kgrp * 4;
                u16x4 o;
#pragma unroll
                for (int i = 0; i < 4; i++) o[i] = f2bf(acc[i] + bias);
                *(u16x4*)vt = o;
            } else {
                unsigned short* dst = qkvb + (size_t)chunk * REGSZ + (size_t)head * HEADSZ + col;
#pragma unroll
                for (int i = 0; i < 4; i++) {
                    int p = p0 + ptile * 16 + kgrp * 4 + i;
                    dst[(size_t)p * 16] = f2bf((acc[i] + bias) * scale);
                }
            }
        }
    }
}

// ---------------- fused NATTEN attention (MFMA) + output projection ----------------
// block: 512 thr = 8 waves = 8 heads; 16 queries (1h x 2w x 8z tile).
// K AND V fragments prefetched before softmax; PV/proj use 2 indep MFMA chains.
__global__ __launch_bounds__(512) void attnproj_kernel(const float* __restrict__ rpb,
                                                       const float* __restrict__ b_proj,
                                                       float* __restrict__ ws,
                                                       float* __restrict__ out) {
    __shared__ unsigned short aol[16 * 128];   // 4 KB attention-out bf16
    __shared__ float rpb_s[8 * 128];           // 4 KB bias tables
    const int tid = threadIdx.x;

    // XCD-aware bijective swizzle (2048 % 8 == 0): contiguous 256-block chunk per XCD
    const int bid = blockIdx.x;
    const int blk = (bid & 7) * 256 + (bid >> 3);

    for (int i = tid; i < 1024; i += 512) {
        int hh = i >> 7, e = i & 127;
        rpb_s[i] = (e < 125) ? rpb[hh * 125 + e] : 0.f;
    }
    __syncthreads();

    const int p0 = blk * 16;
    const int h0 = p0 >> 9;
    const int w0 = (p0 >> 3) & 63;
    const int wv = tid >> 6, lane = tid & 63;
    const int head = wv;
    const int g = lane >> 4;          // row-group
    const int qcol = lane & 15;       // query (as C-col / B-col); also key/d row for A loads
    const int lw = qcol >> 3, qz = qcol & 7;
    const int w = w0 + lw, z = qz;

    // ANCHORED h window: rows sh..sh+2 are exactly the reference window (h uniform)
    const int sh = min(max(h0 - 1, 0), 61);
    const int dh = sh - h0 + 2;
    const int sw = min(max(w - 1, 0), 61);
    const int sz = min(max(z - 1, 0), 5);

    unsigned wmask = 0, zmask = 0;
#pragma unroll
    for (int iw = 0; iw < 4; iw++) {
        int W = w0 - 1 + iw;
        if (W >= sw && W <= sw + 2) wmask |= 1u << iw;
    }
#pragma unroll
    for (int zp = 0; zp < 8; zp++) {
        if (zp >= sz && zp <= sz + 2) zmask |= 1u << zp;
    }

    int Wc[4];
#pragma unroll
    for (int iw = 0; iw < 4; iw++) Wc[iw] = min(max(w0 - 1 + iw, 0), 63);

    const unsigned short* qkvb = (const unsigned short*)(ws + QKV_F_OFF);
    const unsigned short* qbase = qkvb + (size_t)head * HEADSZ;
    const unsigned short* kbase = qkvb + (size_t)REGSZ + (size_t)head * HEADSZ;
    const unsigned short* vtb  = qkvb + 2 * (size_t)REGSZ + (size_t)(head * 16) * HWZ;

    // ---- prefetch: Q, all K fragments, all V fragments (13 independent 8B loads) ----
    s16x4 bq = *(const s16x4*)(qbase + (size_t)(p0 + qcol) * 16 + g * 4);

    const int iwlA = qcol >> 3, zpA = qcol & 7;    // logits A-row decode
    const int iwlV = g >> 1,   zp0V = (g & 1) * 4; // PV A k-decode
    s16x4 ak[6], av[6];
#pragma unroll
    for (int mt = 0; mt < 6; mt++) {
        int iwA = (mt & 1) * 2 + iwlA;
        int pkK = (sh + (mt >> 1)) * 512 + Wc[iwA] * 8 + zpA;
        ak[mt] = *(const s16x4*)(kbase + (size_t)pkK * 16 + g * 4);
        int iwV = (mt & 1) * 2 + iwlV;
        int pkV = (sh + (mt >> 1)) * 512 + Wc[iwV] * 8 + zp0V;
        av[mt] = *(const s16x4*)(vtb + (size_t)qcol * HWZ + pkV);
    }

    // ---- logits: 6 independent Mtiles ----
    f32x4 acc[6];
#pragma unroll
    for (int mt = 0; mt < 6; mt++) {
        f32x4 zero = {0.f, 0.f, 0.f, 0.f};
        acc[mt] = __builtin_amdgcn_mfma_f32_16x16x16bf16_1k(ak[mt], bq, zero, 0, 0, 0);
    }

    // ---- mask + bias + softmax ----
    const float* bt = rpb_s + head * 128;
    float lv[24];
    float lmax = -1e30f;
#pragma unroll
    for (int mt = 0; mt < 6; mt++) {
        int ih = mt >> 1;
#pragma unroll
        for (int r = 0; r < 4; r++) {
            int krow = g * 4 + r;
            int iw = (mt & 1) * 2 + (krow >> 3);
            int zp = krow & 7;
            int ok = ((wmask >> iw) & 1) & ((zmask >> zp) & 1);
            int idx = (dh + ih) * 25 + (iw + 1 - lw) * 5 + (zp - z + 2);
            idx = ok ? idx : 62;
            float lg = ok ? (acc[mt][r] + bt[idx]) : -1e30f;
            lv[mt * 4 + r] = lg;
            lmax = fmaxf(lmax, lg);
        }
    }
    lmax = fmaxf(lmax, __shfl_xor(lmax, 16));
    lmax = fmaxf(lmax, __shfl_xor(lmax, 32));
    float ssum = 0.f;
#pragma unroll
    for (int i = 0; i < 24; i++) {
        float pexp = __expf(lv[i] - lmax);
        lv[i] = pexp;
        ssum += pexp;
    }
    ssum += __shfl_xor(ssum, 16);
    ssum += __shfl_xor(ssum, 32);
    float inv = 1.f / ssum;

    // P -> bf16 fragments (B operand layout == accumulator layout)
    s16x4 pb[6];
#pragma unroll
    for (int mt = 0; mt < 6; mt++)
#pragma unroll
        for (int r = 0; r < 4; r++)
            pb[mt][r] = (short)f2bf(lv[mt * 4 + r]);

    // ---- PV: out(16d x 16q) = V^T @ P, two independent chains ----
    f32x4 o0 = {0.f, 0.f, 0.f, 0.f}, o1 = {0.f, 0.f, 0.f, 0.f};
    o0 = __builtin_amdgcn_mfma_f32_16x16x16bf16_1k(av[0], pb[0], o0, 0, 0, 0);
    o1 = __builtin_amdgcn_mfma_f32_16x16x16bf16_1k(av[1], pb[1], o1, 0, 0, 0);
    o0 = __builtin_amdgcn_mfma_f32_16x16x16bf16_1k(av[2], pb[2], o0, 0, 0, 0);
    o1 = __builtin_amdgcn_mfma_f32_16x16x16bf16_1k(av[3], pb[3], o1, 0, 0, 0);
    o0 = __builtin_amdgcn_mfma_f32_16x16x16bf16_1k(av[4], pb[4], o0, 0, 0, 0);
    o1 = __builtin_amdgcn_mfma_f32_16x16x16bf16_1k(av[5], pb[5], o1, 0, 0, 0);
    f32x4 oacc = o0 + o1;

    // write to aol[q][c], 16B groups swizzled by q&15 (c = head*16 + d, d = 4g+r)
#pragma unroll
    for (int r = 0; r < 4; r++) {
        int c = head * 16 + g * 4 + r;
        aol[qcol * 128 + (((c >> 3) ^ qcol) << 3) + (c & 7)] = f2bf(oacc[r] * inv);
    }
    __syncthreads();

    // ---- proj GEMM: out[p][j] = sum_c' ao[p][c'] * wT[j][c'], two chains ----
    const unsigned short* wpt = (const unsigned short*)(ws + WT_F_OFF);
    const unsigned short* ap = aol + qcol * 128;
    u16x8 a[4];
#pragma unroll
    for (int ks = 0; ks < 4; ks++) {
        a[ks] = *(const u16x8*)(ap + (((ks * 4 + g) ^ qcol) << 3));
    }
    int j = wv * 16 + qcol;
    const unsigned short* bp = wpt + j * 128;
    u16x8 b0 = *(const u16x8*)(bp + ((0 * 4 + g) << 3));
    u16x8 b1 = *(const u16x8*)(bp + ((1 * 4 + g) << 3));
    u16x8 b2 = *(const u16x8*)(bp + ((2 * 4 + g) << 3));
    u16x8 b3 = *(const u16x8*)(bp + ((3 * 4 + g) << 3));
    f32x4 p0a = {0.f, 0.f, 0.f, 0.f}, p1a = {0.f, 0.f, 0.f, 0.f};
    p0a = __builtin_amdgcn_mfma_f32_16x16x32_bf16(__builtin_bit_cast(bf16x8, a[0]),
            __builtin_bit_cast(bf16x8, b0), p0a, 0, 0, 0);
    p1a = __builtin_amdgcn_mfma_f32_16x16x32_bf16(__builtin_bit_cast(bf16x8, a[1]),
            __builtin_bit_cast(bf16x8, b1), p1a, 0, 0, 0);
    p0a = __builtin_amdgcn_mfma_f32_16x16x32_bf16(__builtin_bit_cast(bf16x8, a[2]),
            __builtin_bit_cast(bf16x8, b2), p0a, 0, 0, 0);
    p1a = __builtin_amdgcn_mfma_f32_16x16x32_bf16(__builtin_bit_cast(bf16x8, a[3]),
            __builtin_bit_cast(bf16x8, b3), p1a, 0, 0, 0);
    f32x4 pacc = p0a + p1a;

    float bias = b_proj[j];
    float4 o4;
    o4.x = pacc[0] + bias; o4.y = pacc[1] + bias;
    o4.z = pacc[2] + bias; o4.w = pacc[3] + bias;
    *(float4*)(out + (size_t)j * HWZ + p0 + g * 4) = o4;
}

extern "C" void kernel_launch(void* const* d_in, const int* in_sizes, int n_in,
                              void* d_out, int out_size, void* d_ws, size_t ws_size,
                              hipStream_t stream) {
    const float* x      = (const float*)d_in[0];
    const float* w_qkv  = (const float*)d_in[1];
    const float* b_qkv  = (const float*)d_in[2];
    const float* rpb    = (const float*)d_in[3];
    const float* w_proj = (const float*)d_in[4];
    const float* b_proj = (const float*)d_in[5];
    float* out = (float*)d_out;
    float* ws  = (float*)d_ws;

    prep_kernel<<<384, 256, 0, stream>>>(x, w_qkv, w_proj, ws);
    qkv_kernel<<<512, 512, 0, stream>>>(x, b_qkv, ws);
    attnproj_kernel<<<2048, 512, 0, stream>>>(rpb, b_proj, ws, out);
}

// Round 11
// 65.841 us; speedup vs baseline: 1.3473x; 1.1282x over previous
//
#include <hip/hip_runtime.h>

#define HWZ 32768   // 64*64*8 spatial positions
#define NH 8
#define HD 16

typedef __bf16 bf16x8 __attribute__((ext_vector_type(8)));
typedef unsigned short u16x8 __attribute__((ext_vector_type(8)));
typedef unsigned short u16x4 __attribute__((ext_vector_type(4)));
typedef short s16x4 __attribute__((ext_vector_type(4)));
typedef float f32x4 __attribute__((ext_vector_type(4)));

// ws layout (float offsets):
// [MU(128) | RS(128) | pad] | bf16 QKV (3*REGSZ u16) | bf16 w_proj^T | bf16 w_qkv^T
// Q: [head][p][d]   K: [head][p][d]   V: [head][d][p]  (transposed!)
#define MU_OFF 0
#define RS_OFF 128
#define QKV_F_OFF 1024
#define HEADSZ (HWZ * 16)                        // ushorts per head
#define REGSZ  (NH * HEADSZ)                     // ushorts per tensor (q/k/v)
#define WT_F_OFF  (QKV_F_OFF + (3 * REGSZ) / 2)  // w_proj^T: 128x128 u16
#define WQT_F_OFF (WT_F_OFF + 8192)              // w_qkv^T: 384x128 u16

__device__ __forceinline__ unsigned short f2bf(float f) {
    unsigned int u = __builtin_bit_cast(unsigned int, f);
    unsigned int r = u + 0x7FFFu + ((u >> 16) & 1u);   // RNE
    return (unsigned short)(r >> 16);
}

// ---------------- merged: per-channel stats (blocks 0..127) + weight transpose (128..255) ----------------
__global__ __launch_bounds__(512) void prep_kernel(const float* __restrict__ x,
                                                   const float* __restrict__ w_qkv,
                                                   const float* __restrict__ w_proj,
                                                   float* __restrict__ ws) {
    int blk = blockIdx.x;
    if (blk < 128) {
        int ch = blk;
        const float4* xp = (const float4*)(x + (size_t)ch * HWZ);
        float s = 0.f, ss = 0.f;
        for (int i = threadIdx.x; i < HWZ / 4; i += 512) {
            float4 v = xp[i];
            s  += v.x + v.y + v.z + v.w;
            ss += v.x*v.x + v.y*v.y + v.z*v.z + v.w*v.w;
        }
        for (int off = 32; off; off >>= 1) {
            s  += __shfl_down(s, off);
            ss += __shfl_down(ss, off);
        }
        __shared__ float as_[8], bs_[8];
        int lane = threadIdx.x & 63, wid = threadIdx.x >> 6;
        if (lane == 0) { as_[wid] = s; bs_[wid] = ss; }
        __syncthreads();
        if (threadIdx.x == 0) {
            float S = 0.f, SS = 0.f;
            for (int w = 0; w < 8; w++) { S += as_[w]; SS += bs_[w]; }
            float mu  = S / (float)HWZ;
            float var = SS / (float)HWZ - mu * mu;
            ws[MU_OFF + ch] = mu;
            ws[RS_OFF + ch] = rsqrtf(var + 1e-5f);
        }
    } else {
        int rr = (blk - 128) * 4 + (threadIdx.x >> 7);   // 0..511 (grid=256 -> exact)
        int c  = threadIdx.x & 127;
        if (rr < 384) {
            unsigned short* wqt = (unsigned short*)(ws + WQT_F_OFF);
            wqt[rr * 128 + c] = f2bf(w_qkv[(size_t)c * 384 + rr]);
        } else if (rr < 512) {
            int j = rr - 384;
            unsigned short* wpt = (unsigned short*)(ws + WT_F_OFF);
            wpt[j * 128 + c] = f2bf(w_proj[(size_t)c * 128 + j]);
        }
    }
}

// ---------------- QKV GEMM via bf16 MFMA ----------------
__global__ __launch_bounds__(512) void qkv_kernel(const float* __restrict__ x,
                                                  const float* __restrict__ b_qkv,
                                                  float* __restrict__ ws) {
    __shared__ unsigned short xs[64 * 128];    // [p][c] bf16, 16B groups XOR-swizzled by p&15
    const int tid = threadIdx.x;
    const int p0 = blockIdx.x * 64;

    // staging: thread = (cgrp, pgrp); 4 rows x 4 positions, vectorized 8B LDS writes
    {
        const int pgrp = tid & 15;        // p = pgrp*4 .. +3
        const int c0   = (tid >> 4) * 4;  // c = c0 .. c0+3
        float4 mu4 = *(const float4*)(ws + MU_OFF + c0);
        float4 rs4 = *(const float4*)(ws + RS_OFF + c0);
        float mus[4] = {mu4.x, mu4.y, mu4.z, mu4.w};
        float rss[4] = {rs4.x, rs4.y, rs4.z, rs4.w};
        unsigned short vals[4][4];        // [ci][pi]
#pragma unroll
        for (int ci = 0; ci < 4; ci++) {
            float4 v = *(const float4*)(x + (size_t)(c0 + ci) * HWZ + p0 + pgrp * 4);
            vals[ci][0] = f2bf((v.x - mus[ci]) * rss[ci]);
            vals[ci][1] = f2bf((v.y - mus[ci]) * rss[ci]);
            vals[ci][2] = f2bf((v.z - mus[ci]) * rss[ci]);
            vals[ci][3] = f2bf((v.w - mus[ci]) * rss[ci]);
        }
        const int c8 = c0 >> 3, cl = c0 & 7;
#pragma unroll
        for (int pi = 0; pi < 4; pi++) {
            int p = pgrp * 4 + pi;
            u16x4 o = {vals[0][pi], vals[1][pi], vals[2][pi], vals[3][pi]};
            *(u16x4*)(xs + p * 128 + ((c8 ^ (p & 15)) << 3) + cl) = o;
        }
    }
    __syncthreads();

    const int wv   = tid >> 6;
    const int lane = tid & 63;
    const int col  = lane & 15;
    const int kgrp = lane >> 4;
    const int ptile = wv & 3;
    const int jq    = wv >> 2;
    const unsigned short* arow = xs + (ptile * 16 + col) * 128;
    const int arow15 = (ptile * 16 + col) & 15;

    u16x8 a[4];
#pragma unroll
    for (int ks = 0; ks < 4; ks++) {
        a[ks] = *(const u16x8*)(arow + (((ks * 4 + kgrp) ^ arow15) << 3));
    }

    const unsigned short* wqt = (const unsigned short*)(ws + WQT_F_OFF);
    unsigned short* qkvb = (unsigned short*)(ws + QKV_F_OFF);

    for (int chunk = 0; chunk < 3; chunk++) {
        float scale = (chunk == 0) ? 0.25f : 1.0f;
#pragma unroll
        for (int jt = 0; jt < 4; jt++) {
            int jl = jq * 64 + jt * 16 + col;
            const unsigned short* brow = wqt + (size_t)(chunk * 128 + jl) * 128;
            f32x4 acc = {0.f, 0.f, 0.f, 0.f};
#pragma unroll
            for (int ks = 0; ks < 4; ks++) {
                u16x8 b = *(const u16x8*)(brow + ((ks * 4 + kgrp) << 3));
                acc = __builtin_amdgcn_mfma_f32_16x16x32_bf16(
                        __builtin_bit_cast(bf16x8, a[ks]),
                        __builtin_bit_cast(bf16x8, b), acc, 0, 0, 0);
            }
            int head = jq * 4 + jt;
            float bias = b_qkv[chunk * 128 + head * 16 + col];
            if (chunk == 2) {
                // V transposed: vt[head][d=col][p]
                unsigned short* vt = qkvb + 2 * (size_t)REGSZ
                                   + ((size_t)(head * 16 + col)) * HWZ
                                   + p0 + ptile * 16 + kgrp * 4;
                u16x4 o;
#pragma unroll
                for (int i = 0; i < 4; i++) o[i] = f2bf(acc[i] + bias);
                *(u16x4*)vt = o;
            } else {
                unsigned short* dst = qkvb + (size_t)chunk * REGSZ + (size_t)head * HEADSZ + col;
#pragma unroll
                for (int i = 0; i < 4; i++) {
                    int p = p0 + ptile * 16 + kgrp * 4 + i;
                    dst[(size_t)p * 16] = f2bf((acc[i] + bias) * scale);
                }
            }
        }
    }
}

// ---------------- fused NATTEN attention (MFMA) + output projection ----------------
// block: 512 thr = 8 waves = 8 heads; TWO 16-query tiles (32 positions, same h-row).
// Per tile: prefetch K+V frags, logits MFMA, masked softmax, PV MFMA -> aol.
// Shared: rpb staging, h-window math, proj B-fragments (reused across tiles).
__global__ __launch_bounds__(512) void attnproj_kernel(const float* __restrict__ rpb,
                                                       const float* __restrict__ b_proj,
                                                       float* __restrict__ ws,
                                                       float* __restrict__ out) {
    __shared__ unsigned short aol[32 * 128];   // 8 KB attention-out bf16
    __shared__ float rpb_s[8 * 128];           // 4 KB bias tables
    const int tid = threadIdx.x;

    // XCD-aware bijective swizzle (1024 % 8 == 0): contiguous 128-block chunk per XCD
    const int bid = blockIdx.x;
    const int blk = (bid & 7) * 128 + (bid >> 3);

    for (int i = tid; i < 1024; i += 512) {
        int hh = i >> 7, e = i & 127;
        rpb_s[i] = (e < 125) ? rpb[hh * 125 + e] : 0.f;
    }
    __syncthreads();

    const int p0 = blk * 32;          // 32 positions, all within one h-row
    const int h0 = p0 >> 9;
    const int w0 = (p0 >> 3) & 63;    // tiles at w0 and w0+2
    const int wv = tid >> 6, lane = tid & 63;
    const int head = wv;
    const int g = lane >> 4;          // row-group
    const int qcol = lane & 15;       // query within tile; also key/d row for A loads
    const int lw = qcol >> 3, qz = qcol & 7;
    const int z = qz;

    // ANCHORED h window (shared by both tiles)
    const int sh = min(max(h0 - 1, 0), 61);
    const int dh = sh - h0 + 2;
    const int sz = min(max(z - 1, 0), 5);
    unsigned zmask = 0;
#pragma unroll
    for (int zp = 0; zp < 8; zp++) {
        if (zp >= sz && zp <= sz + 2) zmask |= 1u << zp;
    }

    const unsigned short* qkvb = (const unsigned short*)(ws + QKV_F_OFF);
    const unsigned short* qbase = qkvb + (size_t)head * HEADSZ;
    const unsigned short* kbase = qkvb + (size_t)REGSZ + (size_t)head * HEADSZ;
    const unsigned short* vtb  = qkvb + 2 * (size_t)REGSZ + (size_t)(head * 16) * HWZ;
    const float* bt = rpb_s + head * 128;

    const int iwlA = qcol >> 3, zpA = qcol & 7;    // logits A-row decode
    const int iwlV = g >> 1,   zp0V = (g & 1) * 4; // PV A k-decode

#pragma unroll
    for (int t = 0; t < 2; t++) {
        const int pt = p0 + t * 16;
        const int w0t = w0 + t * 2;
        const int w = w0t + lw;
        const int sw = min(max(w - 1, 0), 61);
        unsigned wmask = 0;
#pragma unroll
        for (int iw = 0; iw < 4; iw++) {
            int W = w0t - 1 + iw;
            if (W >= sw && W <= sw + 2) wmask |= 1u << iw;
        }
        int Wc[4];
#pragma unroll
        for (int iw = 0; iw < 4; iw++) Wc[iw] = min(max(w0t - 1 + iw, 0), 63);

        // ---- prefetch: Q, all K fragments, all V fragments ----
        s16x4 bq = *(const s16x4*)(qbase + (size_t)(pt + qcol) * 16 + g * 4);
        s16x4 ak[6], av[6];
#pragma unroll
        for (int mt = 0; mt < 6; mt++) {
            int iwA = (mt & 1) * 2 + iwlA;
            int pkK = (sh + (mt >> 1)) * 512 + Wc[iwA] * 8 + zpA;
            ak[mt] = *(const s16x4*)(kbase + (size_t)pkK * 16 + g * 4);
            int iwV = (mt & 1) * 2 + iwlV;
            int pkV = (sh + (mt >> 1)) * 512 + Wc[iwV] * 8 + zp0V;
            av[mt] = *(const s16x4*)(vtb + (size_t)qcol * HWZ + pkV);
        }

        // ---- logits: 6 independent Mtiles ----
        f32x4 acc[6];
#pragma unroll
        for (int mt = 0; mt < 6; mt++) {
            f32x4 zero = {0.f, 0.f, 0.f, 0.f};
            acc[mt] = __builtin_amdgcn_mfma_f32_16x16x16bf16_1k(ak[mt], bq, zero, 0, 0, 0);
        }

        // ---- mask + bias + softmax ----
        float lv[24];
        float lmax = -1e30f;
#pragma unroll
        for (int mt = 0; mt < 6; mt++) {
            int ih = mt >> 1;
#pragma unroll
            for (int r = 0; r < 4; r++) {
                int krow = g * 4 + r;
                int iw = (mt & 1) * 2 + (krow >> 3);
                int zp = krow & 7;
                int ok = ((wmask >> iw) & 1) & ((zmask >> zp) & 1);
                int idx = (dh + ih) * 25 + (iw + 1 - lw) * 5 + (zp - z + 2);
                idx = ok ? idx : 62;
                float lg = ok ? (acc[mt][r] + bt[idx]) : -1e30f;
                lv[mt * 4 + r] = lg;
                lmax = fmaxf(lmax, lg);
            }
        }
        lmax = fmaxf(lmax, __shfl_xor(lmax, 16));
        lmax = fmaxf(lmax, __shfl_xor(lmax, 32));
        float ssum = 0.f;
#pragma unroll
        for (int i = 0; i < 24; i++) {
            float pexp = __expf(lv[i] - lmax);
            lv[i] = pexp;
            ssum += pexp;
        }
        ssum += __shfl_xor(ssum, 16);
        ssum += __shfl_xor(ssum, 32);
        float inv = 1.f / ssum;

        // P -> bf16 fragments (B operand layout == accumulator layout)
        s16x4 pb[6];
#pragma unroll
        for (int mt = 0; mt < 6; mt++)
#pragma unroll
            for (int r = 0; r < 4; r++)
                pb[mt][r] = (short)f2bf(lv[mt * 4 + r]);

        // ---- PV: out(16d x 16q) = V^T @ P, two independent chains ----
        f32x4 o0 = {0.f, 0.f, 0.f, 0.f}, o1 = {0.f, 0.f, 0.f, 0.f};
        o0 = __builtin_amdgcn_mfma_f32_16x16x16bf16_1k(av[0], pb[0], o0, 0, 0, 0);
        o1 = __builtin_amdgcn_mfma_f32_16x16x16bf16_1k(av[1], pb[1], o1, 0, 0, 0);
        o0 = __builtin_amdgcn_mfma_f32_16x16x16bf16_1k(av[2], pb[2], o0, 0, 0, 0);
        o1 = __builtin_amdgcn_mfma_f32_16x16x16bf16_1k(av[3], pb[3], o1, 0, 0, 0);
        o0 = __builtin_amdgcn_mfma_f32_16x16x16bf16_1k(av[4], pb[4], o0, 0, 0, 0);
        o1 = __builtin_amdgcn_mfma_f32_16x16x16bf16_1k(av[5], pb[5], o1, 0, 0, 0);
        f32x4 oacc = o0 + o1;

        // write to aol[q + t*16][c], 16B groups swizzled by q&15 (row&15 == qcol)
#pragma unroll
        for (int r = 0; r < 4; r++) {
            int c = head * 16 + g * 4 + r;
            aol[(t * 16 + qcol) * 128 + (((c >> 3) ^ qcol) << 3) + (c & 7)] = f2bf(oacc[r] * inv);
        }
    }

    // proj B-fragments: load BEFORE the barrier (independent of aol)
    const unsigned short* wpt = (const unsigned short*)(ws + WT_F_OFF);
    const int j = wv * 16 + qcol;
    const unsigned short* bp = wpt + j * 128;
    u16x8 b0 = *(const u16x8*)(bp + ((0 * 4 + g) << 3));
    u16x8 b1 = *(const u16x8*)(bp + ((1 * 4 + g) << 3));
    u16x8 b2 = *(const u16x8*)(bp + ((2 * 4 + g) << 3));
    u16x8 b3 = *(const u16x8*)(bp + ((3 * 4 + g) << 3));
    float bias = b_proj[j];
    __syncthreads();

    // ---- proj GEMM: both position-tiles against the same B fragments ----
#pragma unroll
    for (int t = 0; t < 2; t++) {
        const unsigned short* ap = aol + (t * 16 + qcol) * 128;
        u16x8 a[4];
#pragma unroll
        for (int ks = 0; ks < 4; ks++) {
            a[ks] = *(const u16x8*)(ap + (((ks * 4 + g) ^ qcol) << 3));
        }
        f32x4 p0a = {0.f, 0.f, 0.f, 0.f}, p1a = {0.f, 0.f, 0.f, 0.f};
        p0a = __builtin_amdgcn_mfma_f32_16x16x32_bf16(__builtin_bit_cast(bf16x8, a[0]),
                __builtin_bit_cast(bf16x8, b0), p0a, 0, 0, 0);
        p1a = __builtin_amdgcn_mfma_f32_16x16x32_bf16(__builtin_bit_cast(bf16x8, a[1]),
                __builtin_bit_cast(bf16x8, b1), p1a, 0, 0, 0);
        p0a = __builtin_amdgcn_mfma_f32_16x16x32_bf16(__builtin_bit_cast(bf16x8, a[2]),
                __builtin_bit_cast(bf16x8, b2), p0a, 0, 0, 0);
        p1a = __builtin_amdgcn_mfma_f32_16x16x32_bf16(__builtin_bit_cast(bf16x8, a[3]),
                __builtin_bit_cast(bf16x8, b3), p1a, 0, 0, 0);
        f32x4 pacc = p0a + p1a;

        float4 o4;
        o4.x = pacc[0] + bias; o4.y = pacc[1] + bias;
        o4.z = pacc[2] + bias; o4.w = pacc[3] + bias;
        *(float4*)(out + (size_t)j * HWZ + p0 + t * 16 + g * 4) = o4;
    }
}

extern "C" void kernel_launch(void* const* d_in, const int* in_sizes, int n_in,
                              void* d_out, int out_size, void* d_ws, size_t ws_size,
                              hipStream_t stream) {
    const float* x      = (const float*)d_in[0];
    const float* w_qkv  = (const float*)d_in[1];
    const float* b_qkv  = (const float*)d_in[2];
    const float* rpb    = (const float*)d_in[3];
    const float* w_proj = (const float*)d_in[4];
    const float* b_proj = (const float*)d_in[5];
    float* out = (float*)d_out;
    float* ws  = (float*)d_ws;

    prep_kernel<<<256, 512, 0, stream>>>(x, w_qkv, w_proj, ws);
    qkv_kernel<<<512, 512, 0, stream>>>(x, b_qkv, ws);
    attnproj_kernel<<<1024, 512, 0, stream>>>(rpb, b_proj, ws, out);
}